// Round 4
// baseline (813.952 us; speedup 1.0000x reference)
//
#include <hip/hip_runtime.h>

// GPT2 attention forward, MI355X bf16-MFMA implementation.
// Outputs (fp32, concat): attn_output [2,2048,1024], attn_weights [2,16,2048,2048],
// k [2,16,2048,64], v [2,16,2048,64].
//
// R3: attn rewritten as single-sweep, deferred-normalization, row-contiguous stores.
//  - Block = 16 q-rows (grid 32 x 128). 4 waves split K-chunks of the same rows.
//  - One K sweep: QK -> exp (masked) -> fp16 Pbuf[16][2048] in LDS; unnormalized
//    l and PV accumulated in the same sweep (halves K traffic, exp, QK MFMA).
//  - PV uses f16 MFMA directly on fp16 P fragments; V stored fp16 by gemm_qkv.
//  - Store phase: each attn_w row written as 8 consecutive 1KB NT insts = 8KB
//    contiguous per row (fill-like DRAM locality), zeros in the same walk.

typedef __attribute__((ext_vector_type(8))) short bf8_t;     // 8 x bf16 (4 VGPRs)
typedef __attribute__((ext_vector_type(4))) float f4_t;      // 4 x f32
typedef __attribute__((ext_vector_type(8))) _Float16 h8_t;   // 8 x f16
typedef __attribute__((ext_vector_type(4))) _Float16 h4_t;   // 4 x f16

#define MFMA(a, b, c)  __builtin_amdgcn_mfma_f32_16x16x32_bf16(a, b, c, 0, 0, 0)
#define MFMAH(a, b, c) __builtin_amdgcn_mfma_f32_16x16x32_f16(a, b, c, 0, 0, 0)

static __device__ __forceinline__ unsigned short f2bf(float f) {
    union { float f; unsigned u; } x; x.f = f;
    unsigned u = x.u;
    return (unsigned short)((u + 0x7fffu + ((u >> 16) & 1u)) >> 16);
}

// async global->LDS, 16B per lane. LDS dest is wave-uniform base + lane*16.
static __device__ __forceinline__ void stage16(const unsigned short* g, unsigned short* lbase) {
    __builtin_amdgcn_global_load_lds(
        (const __attribute__((address_space(1))) unsigned int*)g,
        (__attribute__((address_space(3))) unsigned int*)lbase, 16, 0, 0);
}

#define NE 4194304ULL
#define AW 134217728ULL

// ---------------- prep kernels ----------------

__global__ void cast_hidden(const float* __restrict__ src, unsigned short* __restrict__ dst) {
    int i = (blockIdx.x * 256 + threadIdx.x) * 4;
    float4 h = *(const float4*)(src + i);
    ushort4 o;
    o.x = f2bf(h.x); o.y = f2bf(h.y); o.z = f2bf(h.z); o.w = f2bf(h.w);
    *(ushort4*)(dst + i) = o;
}

__global__ void transpose_w(const float* __restrict__ wq, const float* __restrict__ wk,
                            const float* __restrict__ wv, const float* __restrict__ wc,
                            unsigned short* __restrict__ wqkvT, unsigned short* __restrict__ wcT) {
    __shared__ float tile[32][33];
    int z = blockIdx.z;
    const float* W = z == 0 ? wq : z == 1 ? wk : z == 2 ? wv : wc;
    unsigned short* dst = (z < 3) ? (wqkvT + (size_t)z * 1024 * 1024) : wcT;
    int x0 = blockIdx.x * 32, y0 = blockIdx.y * 32;
    int tx = threadIdx.x, ty = threadIdx.y;
#pragma unroll
    for (int i = 0; i < 4; ++i)
        tile[ty + i * 8][tx] = W[(size_t)(y0 + ty + i * 8) * 1024 + x0 + tx];
    __syncthreads();
#pragma unroll
    for (int i = 0; i < 4; ++i)
        dst[(size_t)(x0 + ty + i * 8) * 1024 + y0 + tx] = f2bf(tile[tx][ty + i * 8]);
}

// ---------------- GEMM core (m97-style: global_load_lds + BK=64 + XOR swizzle) ------------

#define GEMM_CORE(A_, B_, KDIM)                                                             \
    const int m0 = blockIdx.y * 128, n0 = blockIdx.x * 128;                                 \
    const int tid = threadIdx.x, w = tid >> 6, lane = tid & 63, ln = lane & 15,             \
              quad = lane >> 4;                                                             \
    const int wm = (w & 1) * 64, wn = (w >> 1) * 64;                                        \
    f4_t acc[4][4] = {};                                                                    \
    for (int kb = 0; kb < (KDIM); kb += 64) {                                               \
        __syncthreads();                                                                    \
        _Pragma("unroll")                                                                   \
        for (int p = 0; p < 4; ++p) {                                                       \
            int t = (w * 4 + p) * 64 + lane;                                                \
            int r = t >> 3, c = (t & 7) ^ (r & 7);                                          \
            stage16(&(A_)[(size_t)(m0 + r) * (KDIM) + kb + c * 8], &As[(w * 4 + p) * 512]); \
            stage16(&(B_)[(size_t)(n0 + r) * (KDIM) + kb + c * 8], &Bs[(w * 4 + p) * 512]); \
        }                                                                                   \
        __syncthreads();                                                                    \
        bf8_t af[2][4], bfm[2][4];                                                          \
        _Pragma("unroll")                                                                   \
        for (int h = 0; h < 2; ++h) {                                                       \
            _Pragma("unroll")                                                               \
            for (int i = 0; i < 4; ++i) {                                                   \
                int c = (h * 4 + quad) ^ (ln & 7);                                          \
                af[h][i] = *(const bf8_t*)&As[(wm + i * 16 + ln) * 64 + c * 8];             \
                bfm[h][i] = *(const bf8_t*)&Bs[(wn + i * 16 + ln) * 64 + c * 8];            \
            }                                                                               \
        }                                                                                   \
        _Pragma("unroll")                                                                   \
        for (int h = 0; h < 2; ++h)                                                         \
            _Pragma("unroll")                                                               \
            for (int i = 0; i < 4; ++i)                                                     \
                _Pragma("unroll")                                                           \
                for (int j = 0; j < 4; ++j)                                                 \
                    acc[i][j] = MFMA(af[h][i], bfm[h][j], acc[i][j]);                       \
    }

__global__ __launch_bounds__(256) void gemm_qkv(
    const unsigned short* __restrict__ A, const unsigned short* __restrict__ BT,
    const float* __restrict__ bq, const float* __restrict__ bk, const float* __restrict__ bv,
    unsigned short* __restrict__ q_bf, unsigned short* __restrict__ k_bf,
    _Float16* __restrict__ vT_h, float* __restrict__ out_k, float* __restrict__ out_v)
{
    __shared__ __align__(16) unsigned short As[128 * 64];
    __shared__ __align__(16) unsigned short Bs[128 * 64];
    GEMM_CORE(A, BT, 1024)
#pragma unroll
    for (int j = 0; j < 4; ++j) {
        int coln = n0 + wn + j * 16 + ln;                 // 0..3071
        int which = coln >> 10, d = coln & 1023, h = d >> 6, e = d & 63;
        float bias = which == 0 ? bq[d] : (which == 1 ? bk[d] : bv[d]);
#pragma unroll
        for (int i = 0; i < 4; ++i) {
#pragma unroll
            for (int v = 0; v < 4; ++v) {
                int row = m0 + wm + i * 16 + quad * 4 + v;
                int b = row >> 11, s = row & 2047;
                float val = acc[i][j][v] + bias;
                size_t hidx = (((size_t)(b * 16 + h)) * 2048 + s) * 64 + e;
                if (which == 0) {
                    q_bf[hidx] = f2bf(val * 0.125f);
                } else if (which == 1) {
                    k_bf[hidx] = f2bf(val);
                    __builtin_nontemporal_store(val, &out_k[hidx]);
                } else {
                    vT_h[((size_t)(b * 16 + h) * 64 + e) * 2048 + s] = (_Float16)val;
                    __builtin_nontemporal_store(val, &out_v[hidx]);
                }
            }
        }
    }
}

__global__ __launch_bounds__(256) void gemm_cproj(
    const unsigned short* __restrict__ A, const unsigned short* __restrict__ BT,
    const float* __restrict__ bc, float* __restrict__ out)
{
    __shared__ __align__(16) unsigned short As[128 * 64];
    __shared__ __align__(16) unsigned short Bs[128 * 64];
    GEMM_CORE(A, BT, 1024)
#pragma unroll
    for (int j = 0; j < 4; ++j) {
        int coln = n0 + wn + j * 16 + ln;
        float bias = bc[coln];
#pragma unroll
        for (int i = 0; i < 4; ++i) {
#pragma unroll
            for (int v = 0; v < 4; ++v) {
                int row = m0 + wm + i * 16 + quad * 4 + v;
                __builtin_nontemporal_store(acc[i][j][v] + bias, &out[(size_t)row * 1024 + coln]);
            }
        }
    }
}

// ---------------- fused causal attention (single-sweep, deferred normalization) ----------
// Block: 16 q-rows [g0, g0+16). Waves take 32-col chunks round-robin (chunk c -> wave c&3).
// Sweep per chunk: QK MFMA -> masked exp -> fp16 Pbuf + l partial + PV (f16 MFMA),
// all unnormalized. Cross-wave reduce l and o via LDS atomics. Store phase: each
// attn_w row written as one contiguous 8KB walk (8 x 1KB NT insts), normalized on the fly.
#define PB 2064   // Pbuf fp16 row stride (2048 + 16 pad: 4128B = 1032 dw = 8 mod 32 banks)

__global__ __launch_bounds__(256) void attn_fused(
    const unsigned short* __restrict__ q_bf,   // [32][2048][64] bf16, pre-scaled by 0.125
    const unsigned short* __restrict__ k_bf,   // [32][2048][64] bf16
    const _Float16* __restrict__ vT_h,         // [32][64][2048] f16
    float* __restrict__ attn_w,                // [32][2048][2048]
    unsigned short* __restrict__ attnpre)      // [4096][1024] bf16
{
    __shared__ _Float16 Pbuf[16 * PB];         // 66 KB
    __shared__ float oatom[16][68];            // 4.25 KB (stride 68: quads 2-way not 4-way)
    __shared__ float lred[16];
    const int bh = blockIdx.x;
    const int g0 = (127 - (int)blockIdx.y) * 16;   // biggest strips dispatched first
    const int tid = threadIdx.x, w = tid >> 6, lane = tid & 63, ln = lane & 15, quad = lane >> 4;

    // zero reduction buffers
    if (tid < 16) lred[tid] = 0.f;
#pragma unroll
    for (int i = 0; i < 5; ++i) {
        int s = tid + i * 256;                 // 16*68 = 1088 slots
        if (s < 16 * 68) ((float*)oatom)[s] = 0.f;
    }
    __syncthreads();

    const unsigned short* qb = q_bf + ((size_t)bh * 2048 + g0) * 64;
    bf8_t aA0 = *(const bf8_t*)&qb[(size_t)ln * 64 + quad * 8];
    bf8_t aA1 = *(const bf8_t*)&qb[(size_t)ln * 64 + 32 + quad * 8];
    const unsigned short* kb_base = k_bf + (size_t)bh * 2048 * 64;
    const _Float16* vt_base = vT_h + (size_t)bh * 64 * 2048;
    const f4_t zf = {0.f, 0.f, 0.f, 0.f};
    const int cend = ((g0 + 16 + 31) >> 5) << 5;   // active cols, mult of 32

    // ---- single sweep: QK -> exp -> Pbuf ; l partial ; PV (unnormalized) ----
    f4_t lv = {0.f, 0.f, 0.f, 0.f};
    f4_t o[4] = {};
    for (int c = w * 32; c < cend; c += 128) {
        bf8_t kf[4];
        h8_t vb[4];
#pragma unroll
        for (int sub = 0; sub < 2; ++sub) {
            const unsigned short* kp = kb_base + (size_t)(c + sub * 16 + ln) * 64 + quad * 8;
            kf[sub * 2] = *(const bf8_t*)kp;
            kf[sub * 2 + 1] = *(const bf8_t*)(kp + 32);
        }
#pragma unroll
        for (int j = 0; j < 4; ++j)
            vb[j] = *(const h8_t*)(vt_base + (size_t)(j * 16 + ln) * 2048 + c + quad * 8);
#pragma unroll
        for (int sub = 0; sub < 2; ++sub) {
            f4_t sc = MFMA(aA0, kf[sub * 2], zf);
            sc = MFMA(aA1, kf[sub * 2 + 1], sc);
            int col = c + sub * 16 + ln;
#pragma unroll
            for (int v = 0; v < 4; ++v) {
                int row = g0 + quad * 4 + v;
                float p = (col <= row) ? __expf(sc[v]) : 0.f;
                lv[v] += p;
                Pbuf[(quad * 4 + v) * PB + col] = (_Float16)p;
            }
        }
        // PV on this chunk (rows = ln, k = chunk cols); Pbuf rows all written by this wave
        h8_t pf = *(const h8_t*)&Pbuf[ln * PB + c + quad * 8];
#pragma unroll
        for (int j = 0; j < 4; ++j) o[j] = MFMAH(pf, vb[j], o[j]);
    }

    // ---- cross-wave reductions ----
#pragma unroll
    for (int m = 1; m < 16; m <<= 1) {
#pragma unroll
        for (int v = 0; v < 4; ++v) lv[v] += __shfl_xor(lv[v], m);
    }
    if (ln == 0) {
#pragma unroll
        for (int v = 0; v < 4; ++v) atomicAdd(&lred[quad * 4 + v], lv[v]);
    }
#pragma unroll
    for (int j = 0; j < 4; ++j)
#pragma unroll
        for (int v = 0; v < 4; ++v)
            atomicAdd(&oatom[quad * 4 + v][j * 16 + ln], o[j][v]);
    __syncthreads();

    // ---- store phase: contiguous 8KB per attn_w row, normalized on the fly ----
    float* awp = attn_w + ((size_t)bh * 2048 + g0) * 2048;
#pragma unroll
    for (int rr = 0; rr < 4; ++rr) {
        int row = w * 4 + rr;
        float linv_r = 1.f / lred[row];
        float* dst = awp + (size_t)row * 2048;
#pragma unroll
        for (int i = 0; i < 8; ++i) {
            int col = i * 256 + lane * 4;
            h4_t ph = *(const h4_t*)&Pbuf[row * PB + col];
            f4_t val;
#pragma unroll
            for (int j = 0; j < 4; ++j)
                val[j] = (col + j < cend) ? (float)ph[j] * linv_r : 0.f;
            __builtin_nontemporal_store(val, (f4_t*)(dst + col));
        }
    }

    // ---- attn_output pre-projection (bf16), normalized ----
    int b = bh >> 4, h = bh & 15;
#pragma unroll
    for (int rr = 0; rr < 4; ++rr) {
        int row = w * 4 + rr;
        float linv_r = 1.f / lred[row];
        attnpre[(size_t)(b * 2048 + g0 + row) * 1024 + h * 64 + lane] =
            f2bf(oatom[row][lane] * linv_r);
    }
}

// ---------------- launch ----------------
extern "C" void kernel_launch(void* const* d_in, const int* in_sizes, int n_in,
                              void* d_out, int out_size, void* d_ws, size_t ws_size,
                              hipStream_t stream)
{
    const float* hs = (const float*)d_in[0];
    const float* wq = (const float*)d_in[1];
    const float* bq = (const float*)d_in[2];
    const float* wk = (const float*)d_in[3];
    const float* bk = (const float*)d_in[4];
    const float* wv = (const float*)d_in[5];
    const float* bv = (const float*)d_in[6];
    const float* wc = (const float*)d_in[7];
    const float* bc = (const float*)d_in[8];

    float* out      = (float*)d_out;
    float* out_aw   = out + NE;
    float* out_k    = out_aw + AW;
    float* out_v    = out_k + NE;

    char* ws = (char*)d_ws;
    unsigned short* hid_bf  = (unsigned short*)(ws);                // 8 MB
    unsigned short* wqkvT   = (unsigned short*)(ws + 8388608);      // 6 MB
    unsigned short* wcT     = (unsigned short*)(ws + 14680064);     // 2 MB
    unsigned short* q_bf    = (unsigned short*)(ws + 16777216);     // 8 MB
    unsigned short* k_bf    = (unsigned short*)(ws + 25165824);     // 8 MB
    _Float16*       vT_h    = (_Float16*)(ws + 33554432);           // 8 MB
    unsigned short* attnpre = (unsigned short*)(ws + 41943040);     // 8 MB

    cast_hidden<<<4096, 256, 0, stream>>>(hs, hid_bf);
    transpose_w<<<dim3(32, 32, 4), dim3(32, 8), 0, stream>>>(wq, wk, wv, wc, wqkvT, wcT);
    gemm_qkv<<<dim3(24, 32), 256, 0, stream>>>(hid_bf, wqkvT, bq, bk, bv,
                                               q_bf, k_bf, vT_h, out_k, out_v);
    attn_fused<<<dim3(32, 128), 256, 0, stream>>>(q_bf, k_bf, vT_h, out_aw, attnpre);
    gemm_cproj<<<dim3(8, 32), 256, 0, stream>>>(attnpre, wcT, bc, out);
}